// Round 8
// baseline (109.852 us; speedup 1.0000x reference)
//
#include <hip/hip_runtime.h>
#include <math.h>

// Problem constants: B=64, D=512, H=W=32 -> N=1024, NH=8, DH=64
#define BATCH  64
#define DCH    512
#define NPOS   1024
#define NH     8
#define NSG    4       // output n-split groups
#define TPB    8       // n-tiles per block
#define NRANGE 32      // n per tile  (NSG*TPB*NRANGE == NPOS)

// ---------------------------------------------------------------------------
// K1 (prep): blocks 0-1: wqT[c*8+h] = 0.125 * sum_d q[h,d]*Wkv[c,h*64+d]
//            blocks 2-5: bias[h*1024+n] = 0.125*(q.pe[n] + q.bkv)
// ---------------------------------------------------------------------------
__global__ __launch_bounds__(256) void k_prep(const float* __restrict__ q,
                                              const float* __restrict__ Wkv,
                                              const float* __restrict__ bkv,
                                              float* __restrict__ wqT,
                                              float* __restrict__ bias) {
    int blk = blockIdx.x;
    if (blk < 2) {
        int c = blk * 256 + threadIdx.x;
        const float4* wrow = (const float4*)(Wkv + (size_t)c * (2 * DCH));
        const float4* q4   = (const float4*)q;
        #pragma unroll
        for (int h = 0; h < NH; ++h) {
            float s = 0.f;
            #pragma unroll
            for (int d4 = 0; d4 < 16; ++d4) {
                float4 a = q4[h * 16 + d4];
                float4 w = wrow[h * 16 + d4];
                s = fmaf(a.x, w.x, fmaf(a.y, w.y, fmaf(a.z, w.z, fmaf(a.w, w.w, s))));
            }
            wqT[c * NH + h] = 0.125f * s;
        }
    } else {
        int n = (blk - 2) * 256 + threadIdx.x;
        float pq[NH];
        #pragma unroll
        for (int h = 0; h < NH; ++h) pq[h] = 0.f;
        const float kfac2 = -13.2877123795494f / 64.f;   // -log2(10000)/64
        for (int i = 0; i < 32; ++i) {
            float dt = exp2f((float)(2 * i) * kfac2);
            float ang = (float)n * dt;
            float sn, cs;
            sincosf(ang, &sn, &cs);
            #pragma unroll
            for (int h = 0; h < NH; ++h)
                pq[h] = fmaf(q[h * 64 + 2 * i], sn,
                        fmaf(q[h * 64 + 2 * i + 1], cs, pq[h]));
        }
        #pragma unroll
        for (int h = 0; h < NH; ++h) {
            float bq = 0.f;
            #pragma unroll 8
            for (int d = 0; d < 64; ++d)
                bq = fmaf(q[h * 64 + d], bkv[h * 64 + d], bq);
            bias[h * NPOS + n] = 0.125f * (pq[h] + bq);
        }
    }
}

// ---------------------------------------------------------------------------
// K2 (flash): grid (NSG=4, B) = 256 blocks (1/CU), 512 threads.
// Each block: 8 tiles of 32 n, ping-pong register prefetch; x read ONCE.
// Thread (w, rg=lane>>3, n8=lane&7) owns rows c0+8k+rg (k<8), n-quad n8.
// Softmax with fixed reference (m=0): p = exp(s); safe since |s| <~ 5.
// ---------------------------------------------------------------------------
struct FlashCtx {
    const float* gx;       // per-thread x base
    const float* bias_p;   // bias + w*NPOS + nb
    float* wqs;
    float (*sred)[NH][NRANGE];
    float (*pbuf)[NRANGE];
    int w, lane, rg, n8, c0;
};

__device__ __forceinline__ void tile_step(const FlashCtx& cx,
                                          float4 (&xc)[8], float4 (&xn)[8],
                                          int tt, bool dopf,
                                          float (&con)[8][NH], float& zlane) {
    if (dopf) {
        #pragma unroll
        for (int k = 0; k < 8; ++k)
            xn[k] = *(const float4*)(cx.gx + (size_t)(8 * k) * NPOS + (tt + 1) * NRANGE);
    }
    // --- dots partials over this thread's 8 rows x 4 n ---
    float acc[NH][4];
    #pragma unroll
    for (int h = 0; h < NH; ++h)
        #pragma unroll
        for (int e = 0; e < 4; ++e) acc[h][e] = 0.f;
    #pragma unroll
    for (int k = 0; k < 8; ++k) {
        int c = cx.c0 + 8 * k + cx.rg;
        float wv[8];
        *(float4*)&wv[0] = *(const float4*)&cx.wqs[c * 8];
        *(float4*)&wv[4] = *(const float4*)&cx.wqs[c * 8 + 4];
        #pragma unroll
        for (int h = 0; h < NH; ++h) {
            acc[h][0] = fmaf(xc[k].x, wv[h], acc[h][0]);
            acc[h][1] = fmaf(xc[k].y, wv[h], acc[h][1]);
            acc[h][2] = fmaf(xc[k].z, wv[h], acc[h][2]);
            acc[h][3] = fmaf(xc[k].w, wv[h], acc[h][3]);
        }
    }
    // butterfly over lane bits 3,4,5 (the 8 rg groups)
    #pragma unroll
    for (int h = 0; h < NH; ++h)
        #pragma unroll
        for (int e = 0; e < 4; ++e) {
            float v = acc[h][e];
            v += __shfl_xor(v, 8);
            v += __shfl_xor(v, 16);
            v += __shfl_xor(v, 32);
            acc[h][e] = v;
        }
    if (cx.rg == 0) {
        #pragma unroll
        for (int h = 0; h < NH; ++h)
            *(float4*)&cx.sred[cx.w][h][cx.n8 * 4] =
                make_float4(acc[h][0], acc[h][1], acc[h][2], acc[h][3]);
    }
    __syncthreads();
    // --- softmax numerators (wave w handles head h=w; lanes 0-31) ---
    if (cx.lane < 32) {
        float s = cx.bias_p[tt * NRANGE + cx.lane];
        #pragma unroll
        for (int o = 0; o < 8; ++o) s += cx.sred[o][cx.w][cx.lane];
        float p = expf(s);           // fixed reference m=0
        zlane += p;
        cx.pbuf[cx.w][cx.lane] = p;
    }
    __syncthreads();
    // --- PV accumulate from registers ---
    float4 pj[NH];
    #pragma unroll
    for (int h = 0; h < NH; ++h)
        pj[h] = *(const float4*)&cx.pbuf[h][cx.n8 * 4];
    #pragma unroll
    for (int k = 0; k < 8; ++k)
        #pragma unroll
        for (int h = 0; h < NH; ++h)
            con[k][h] = fmaf(xc[k].x, pj[h].x, fmaf(xc[k].y, pj[h].y,
                        fmaf(xc[k].z, pj[h].z, fmaf(xc[k].w, pj[h].w, con[k][h]))));
}

__global__ __launch_bounds__(512, 2) void k_flash(const float* __restrict__ x,
                                                  const float* __restrict__ wqT,
                                                  const float* __restrict__ bias,
                                                  float* __restrict__ apart,  // [NSG][B][NH][DCH]
                                                  float* __restrict__ mz) {   // [NSG][B][16]
    __shared__ float wqs[DCH * NH];          // 16 KB
    __shared__ float sred[8][NH][NRANGE];    // 8 KB
    __shared__ float pbuf[NH][NRANGE];       // 1 KB

    int b = blockIdx.y, nsg = blockIdx.x;
    int t = threadIdx.x, w = t >> 6, lane = t & 63;
    int rg = lane >> 3, n8 = lane & 7;
    int c0 = w * 64;
    int nb = nsg * (TPB * NRANGE);

    {   // stage wq -> LDS (coalesced)
        const float4* s = (const float4*)wqT;
        float4* d = (float4*)wqs;
        d[t] = s[t]; d[t + 512] = s[t + 512];
    }
    __syncthreads();

    FlashCtx cx;
    cx.gx = x + ((size_t)b * DCH + c0 + rg) * NPOS + nb + n8 * 4;
    cx.bias_p = bias + w * NPOS + nb;
    cx.wqs = wqs; cx.sred = sred; cx.pbuf = pbuf;
    cx.w = w; cx.lane = lane; cx.rg = rg; cx.n8 = n8; cx.c0 = c0;

    float con[8][NH];
    #pragma unroll
    for (int k = 0; k < 8; ++k)
        #pragma unroll
        for (int h = 0; h < NH; ++h) con[k][h] = 0.f;
    float zlane = 0.f;

    float4 xa[8], xb[8];
    #pragma unroll
    for (int k = 0; k < 8; ++k)
        xa[k] = *(const float4*)(cx.gx + (size_t)(8 * k) * NPOS);

    #pragma unroll 1
    for (int it = 0; it < TPB; it += 2) {
        tile_step(cx, xa, xb, it,     true,              con, zlane);
        tile_step(cx, xb, xa, it + 1, (it + 2) < TPB,    con, zlane);
    }

    // --- epilogue: reduce PV over n8 (lane bits 0-2), store apart ---
    size_t abase = ((size_t)nsg * BATCH + b) * (NH * DCH);
    #pragma unroll
    for (int k = 0; k < 8; ++k) {
        #pragma unroll
        for (int h = 0; h < NH; ++h) {
            float v = con[k][h];
            v += __shfl_xor(v, 1);
            v += __shfl_xor(v, 2);
            v += __shfl_xor(v, 4);
            con[k][h] = v;
        }
        float val = con[k][0];
        val = (n8 == 1) ? con[k][1] : val;
        val = (n8 == 2) ? con[k][2] : val;
        val = (n8 == 3) ? con[k][3] : val;
        val = (n8 == 4) ? con[k][4] : val;
        val = (n8 == 5) ? con[k][5] : val;
        val = (n8 == 6) ? con[k][6] : val;
        val = (n8 == 7) ? con[k][7] : val;
        apart[abase + (size_t)n8 * DCH + (c0 + 8 * k + rg)] = val;
    }
    // --- Z reduce (lanes 0-31 hold zlane for head w) ---
    float zs = zlane;
    zs += __shfl_xor(zs, 1);
    zs += __shfl_xor(zs, 2);
    zs += __shfl_xor(zs, 4);
    zs += __shfl_xor(zs, 8);
    zs += __shfl_xor(zs, 16);
    if (lane == 0) {
        float* mzp = mz + ((size_t)nsg * BATCH + b) * 2 * NH;
        mzp[w]      = 0.f;   // fixed reference max
        mzp[NH + w] = zs;
    }
}

// ---------------------------------------------------------------------------
// K3: combine NSG partials + output GEMV. grid (B, 2), 512 threads.
// ---------------------------------------------------------------------------
__global__ __launch_bounds__(512) void k_comb(const float* __restrict__ apart,
                                              const float* __restrict__ mz,
                                              const float* __restrict__ Wkv,
                                              const float* __restrict__ bkv,
                                              float* __restrict__ out) {
    __shared__ float as[NH * DCH];
    __shared__ float red[2][256];
    int b = blockIdx.x, half = blockIdx.y, t = threadIdx.x;
    int h = t >> 6;

    float M = -1e30f;
    #pragma unroll
    for (int j = 0; j < NSG; ++j)
        M = fmaxf(M, mz[((size_t)j * BATCH + b) * 2 * NH + h]);
    float Z = 0.f, fj[NSG];
    #pragma unroll
    for (int j = 0; j < NSG; ++j) {
        const float* mzp = mz + ((size_t)j * BATCH + b) * 2 * NH;
        fj[j] = expf(mzp[h] - M);
        Z = fmaf(fj[j], mzp[NH + h], Z);
    }
    float invZ = 1.f / Z;

    int e0 = t * 8;
    float v[8];
    #pragma unroll
    for (int k = 0; k < 8; ++k) v[k] = 0.f;
    #pragma unroll
    for (int j = 0; j < NSG; ++j) {
        const float* src = apart + ((size_t)j * BATCH + b) * (NH * DCH) + e0;
        float4 lo = *(const float4*)(src);
        float4 hi = *(const float4*)(src + 4);
        v[0] = fmaf(fj[j], lo.x, v[0]);
        v[1] = fmaf(fj[j], lo.y, v[1]);
        v[2] = fmaf(fj[j], lo.z, v[2]);
        v[3] = fmaf(fj[j], lo.w, v[3]);
        v[4] = fmaf(fj[j], hi.x, v[4]);
        v[5] = fmaf(fj[j], hi.y, v[5]);
        v[6] = fmaf(fj[j], hi.z, v[6]);
        v[7] = fmaf(fj[j], hi.w, v[7]);
    }
    #pragma unroll
    for (int k = 0; k < 8; ++k) as[e0 + k] = v[k] * invZ;
    __syncthreads();

    int o  = t & 255;
    int cp = t >> 8;
    int hd = half * 256 + o;
    int ho = hd >> 6;
    float a0 = 0.f, a1 = 0.f, a2 = 0.f, a3 = 0.f;
    const float* wp  = Wkv + DCH + hd;
    const float* apr = as + ho * DCH;
    int cbeg = cp * 256;
    #pragma unroll 4
    for (int c = cbeg; c < cbeg + 256; c += 4) {
        a0 = fmaf(apr[c],     wp[(size_t)c * (2 * DCH)],       a0);
        a1 = fmaf(apr[c + 1], wp[(size_t)(c + 1) * (2 * DCH)], a1);
        a2 = fmaf(apr[c + 2], wp[(size_t)(c + 2) * (2 * DCH)], a2);
        a3 = fmaf(apr[c + 3], wp[(size_t)(c + 3) * (2 * DCH)], a3);
    }
    red[cp][o] = (a0 + a1) + (a2 + a3);
    __syncthreads();
    if (t < 256) {
        int hd2 = half * 256 + t;
        out[(size_t)b * DCH + hd2] = bkv[DCH + hd2] + red[0][t] + red[1][t];
    }
}

// ---------------------------------------------------------------------------
extern "C" void kernel_launch(void* const* d_in, const int* in_sizes, int n_in,
                              void* d_out, int out_size, void* d_ws, size_t ws_size,
                              hipStream_t stream) {
    const float* x   = (const float*)d_in[0];   // (64, 512, 32, 32)
    const float* q   = (const float*)d_in[1];   // (1, 8, 1, 64)
    const float* Wkv = (const float*)d_in[2];   // (512, 1024)
    const float* bkv = (const float*)d_in[3];   // (1024,)
    float* out = (float*)d_out;                 // (64, 512)

    float* ws    = (float*)d_ws;
    float* wqT   = ws;                                      // 512*8
    float* bias  = wqT + DCH * NH;                          // 8*1024
    float* apart = bias + NH * NPOS;                        // 4*64*4096 = 4 MiB
    float* mz    = apart + (size_t)NSG * BATCH * NH * DCH;  // 4*64*16

    hipLaunchKernelGGL(k_prep,  dim3(6),           dim3(256), 0, stream, q, Wkv, bkv, wqT, bias);
    hipLaunchKernelGGL(k_flash, dim3(NSG, BATCH),  dim3(512), 0, stream, x, wqT, bias, apart, mz);
    hipLaunchKernelGGL(k_comb,  dim3(BATCH, 2),    dim3(512), 0, stream, apart, mz, Wkv, bkv, out);
}

// Round 9
// 86.019 us; speedup vs baseline: 1.2771x; 1.2771x over previous
//
#include <hip/hip_runtime.h>
#include <math.h>

// Problem constants: B=64, D=512, H=W=32 -> N=1024, NH=8, DH=64
#define BATCH  64
#define DCH    512
#define NPOS   1024
#define NH     8
#define NSPLIT 16
#define NRANGE 64      // n per block tile

// ---------------------------------------------------------------------------
// K1 (prep): blocks 0-1: wqT[c*8+h] = 0.125 * sum_d q[h,d]*Wkv[c,h*64+d]
//            blocks 2-5: bias[h*1024+n] = 0.125*(q.pe[n] + q.bkv)
// ---------------------------------------------------------------------------
__global__ __launch_bounds__(256) void k_prep(const float* __restrict__ q,
                                              const float* __restrict__ Wkv,
                                              const float* __restrict__ bkv,
                                              float* __restrict__ wqT,
                                              float* __restrict__ bias) {
    int blk = blockIdx.x;
    if (blk < 2) {
        int c = blk * 256 + threadIdx.x;
        const float4* wrow = (const float4*)(Wkv + (size_t)c * (2 * DCH));
        const float4* q4   = (const float4*)q;
        #pragma unroll
        for (int h = 0; h < NH; ++h) {
            float s = 0.f;
            #pragma unroll
            for (int d4 = 0; d4 < 16; ++d4) {
                float4 a = q4[h * 16 + d4];
                float4 w = wrow[h * 16 + d4];
                s = fmaf(a.x, w.x, fmaf(a.y, w.y, fmaf(a.z, w.z, fmaf(a.w, w.w, s))));
            }
            wqT[c * NH + h] = 0.125f * s;
        }
    } else {
        int n = (blk - 2) * 256 + threadIdx.x;
        float pq[NH];
        #pragma unroll
        for (int h = 0; h < NH; ++h) pq[h] = 0.f;
        const float kfac2 = -13.2877123795494f / 64.f;   // -log2(10000)/64
        for (int i = 0; i < 32; ++i) {
            float dt = exp2f((float)(2 * i) * kfac2);
            float ang = (float)n * dt;
            float sn, cs;
            sincosf(ang, &sn, &cs);
            #pragma unroll
            for (int h = 0; h < NH; ++h)
                pq[h] = fmaf(q[h * 64 + 2 * i], sn,
                        fmaf(q[h * 64 + 2 * i + 1], cs, pq[h]));
        }
        #pragma unroll
        for (int h = 0; h < NH; ++h) {
            float bq = 0.f;
            #pragma unroll 8
            for (int d = 0; d < 64; ++d)
                bq = fmaf(q[h * 64 + d], bkv[h * 64 + d], bq);
            bias[h * NPOS + n] = 0.125f * (pq[h] + bq);
        }
    }
}

// ---------------------------------------------------------------------------
// K2 (flash): grid (NSPLIT=16, B) = 1024 blocks, 512 threads, 4 blocks/CU.
//  phase 1 (dots): n-in-lane (lane = n), wave w owns c-stripe [w*64,w*64+64).
//    x loads coalesced dwords (8 in flight); weights are WAVE-UNIFORM ->
//    s_load + SGPR-operand FMA. No LDS reads, no shuffles.
//  phase 2: wave h = head h, full-wave softmax over the 64-n tile.
//  phase 3 (PV): lane=(rg=l>>2 -> 16 rows, nq=l&3); 4 c x 16 n per thread;
//    p broadcast via LDS b128; quad xor1/xor2 reduce; x re-read from L2/L3.
// LDS: sred 16 KB + pbuf 2 KB = 18 KB.
// ---------------------------------------------------------------------------
__global__ __launch_bounds__(512) void k_flash(const float* __restrict__ x,
                                               const float* __restrict__ wqT,
                                               const float* __restrict__ bias,
                                               float* __restrict__ apart,  // [NSPLIT][B][NH][DCH]
                                               float* __restrict__ mz) {   // [NSPLIT][B][16]
    __shared__ float sred[8][NH][NRANGE];  // 16 KB  [wave][h][n]
    __shared__ float pbuf[NH][NRANGE];     // 2 KB

    int b = blockIdx.y, ns = blockIdx.x;
    int t = threadIdx.x;
    int w = __builtin_amdgcn_readfirstlane(t >> 6);   // wave id (uniform)
    int lane = t & 63;
    int n0 = ns * NRANGE;
    int c0 = w * 64;

    // ---------------- phase 1: dots, n-in-lane, SGPR weights ----------------
    {
        const float* xp = x + ((size_t)b * DCH + c0) * NPOS + n0 + lane;
        const float* wr = wqT + c0 * NH;   // uniform base
        float acc[NH];
        #pragma unroll
        for (int h = 0; h < NH; ++h) acc[h] = 0.f;

        float xv[8], xn[8];
        #pragma unroll
        for (int u = 0; u < 8; ++u) xv[u] = xp[(size_t)u * NPOS];

        #pragma unroll
        for (int g = 0; g < 8; ++g) {
            if (g < 7) {
                #pragma unroll
                for (int u = 0; u < 8; ++u)
                    xn[u] = xp[(size_t)(8 * g + 8 + u) * NPOS];
            }
            #pragma unroll
            for (int u = 0; u < 8; ++u) {
                float wv[8];
                *(float4*)&wv[0] = *(const float4*)(wr + (8 * g + u) * NH);
                *(float4*)&wv[4] = *(const float4*)(wr + (8 * g + u) * NH + 4);
                #pragma unroll
                for (int h = 0; h < NH; ++h)
                    acc[h] = fmaf(xv[u], wv[h], acc[h]);
            }
            if (g < 7) {
                #pragma unroll
                for (int u = 0; u < 8; ++u) xv[u] = xn[u];
            }
        }
        #pragma unroll
        for (int h = 0; h < NH; ++h) sred[w][h][lane] = acc[h];
    }
    __syncthreads();

    // ---------------- phase 2: softmax (wave w = head w) ----------------
    {
        float s = bias[w * NPOS + n0 + lane];
        #pragma unroll
        for (int o = 0; o < 8; ++o) s += sred[o][w][lane];
        float m = s;
        #pragma unroll
        for (int o = 32; o; o >>= 1) m = fmaxf(m, __shfl_xor(m, o));
        float p = expf(s - m);
        float z = p;
        #pragma unroll
        for (int o = 32; o; o >>= 1) z += __shfl_xor(z, o);
        pbuf[w][lane] = p;
        if (lane == 0) {
            float* mzp = mz + ((size_t)ns * BATCH + b) * 2 * NH;
            mzp[w]      = m;
            mzp[NH + w] = z;
        }
    }
    __syncthreads();

    // ---------------- phase 3: PV, c-in-lane, x from L2/L3 ----------------
    {
        int rg = lane >> 2;   // 16 rows
        int nq = lane & 3;    // 4 n-quads; 16 n per thread over j=0..3
        const float* xr = x + ((size_t)b * DCH + c0 + rg) * NPOS + n0 + nq * 4;

        float con[4][NH];
        #pragma unroll
        for (int cp = 0; cp < 4; ++cp)
            #pragma unroll
            for (int h = 0; h < NH; ++h) con[cp][h] = 0.f;

        #pragma unroll
        for (int j = 0; j < 4; ++j) {
            float4 xv4[4];
            #pragma unroll
            for (int cp = 0; cp < 4; ++cp)
                xv4[cp] = *(const float4*)(xr + (size_t)(cp * 16) * NPOS + j * 16);
            float4 pj[NH];
            #pragma unroll
            for (int h = 0; h < NH; ++h)
                pj[h] = *(const float4*)&pbuf[h][j * 16 + nq * 4];
            #pragma unroll
            for (int cp = 0; cp < 4; ++cp)
                #pragma unroll
                for (int h = 0; h < NH; ++h)
                    con[cp][h] = fmaf(xv4[cp].x, pj[h].x, fmaf(xv4[cp].y, pj[h].y,
                                 fmaf(xv4[cp].z, pj[h].z, fmaf(xv4[cp].w, pj[h].w, con[cp][h]))));
        }

        // reduce over nq (xor1, xor2) and store
        #pragma unroll
        for (int cp = 0; cp < 4; ++cp)
            #pragma unroll
            for (int h = 0; h < NH; ++h) {
                float v = con[cp][h];
                v += __shfl_xor(v, 1);
                v += __shfl_xor(v, 2);
                con[cp][h] = v;
            }

        size_t abase = ((size_t)ns * BATCH + b) * (NH * DCH);
        #pragma unroll
        for (int cp = 0; cp < 4; ++cp) {
            int c = c0 + cp * 16 + rg;
            float lo = (nq == 0) ? con[cp][0] : (nq == 1) ? con[cp][1]
                     : (nq == 2) ? con[cp][2] : con[cp][3];
            float hi = (nq == 0) ? con[cp][4] : (nq == 1) ? con[cp][5]
                     : (nq == 2) ? con[cp][6] : con[cp][7];
            apart[abase + (size_t)nq * DCH + c]       = lo;
            apart[abase + (size_t)(nq + 4) * DCH + c] = hi;
        }
    }
}

// ---------------------------------------------------------------------------
// K3: combine NSPLIT partials + output GEMV. grid (B, 2), 512 threads.
// ---------------------------------------------------------------------------
__global__ __launch_bounds__(512) void k_comb(const float* __restrict__ apart,
                                              const float* __restrict__ mz,
                                              const float* __restrict__ Wkv,
                                              const float* __restrict__ bkv,
                                              float* __restrict__ out) {
    __shared__ float as[NH * DCH];
    __shared__ float red[2][256];
    int b = blockIdx.x, half = blockIdx.y, t = threadIdx.x;
    int h = t >> 6;

    float M = -1e30f;
    #pragma unroll
    for (int j = 0; j < NSPLIT; ++j)
        M = fmaxf(M, mz[((size_t)j * BATCH + b) * 2 * NH + h]);
    float Z = 0.f, fj[NSPLIT];
    #pragma unroll
    for (int j = 0; j < NSPLIT; ++j) {
        const float* mzp = mz + ((size_t)j * BATCH + b) * 2 * NH;
        fj[j] = expf(mzp[h] - M);
        Z = fmaf(fj[j], mzp[NH + h], Z);
    }
    float invZ = 1.f / Z;

    int e0 = t * 8;
    float v[8];
    #pragma unroll
    for (int k = 0; k < 8; ++k) v[k] = 0.f;
    #pragma unroll 4
    for (int j = 0; j < NSPLIT; ++j) {
        const float* src = apart + ((size_t)j * BATCH + b) * (NH * DCH) + e0;
        float4 lo = *(const float4*)(src);
        float4 hi = *(const float4*)(src + 4);
        v[0] = fmaf(fj[j], lo.x, v[0]);
        v[1] = fmaf(fj[j], lo.y, v[1]);
        v[2] = fmaf(fj[j], lo.z, v[2]);
        v[3] = fmaf(fj[j], lo.w, v[3]);
        v[4] = fmaf(fj[j], hi.x, v[4]);
        v[5] = fmaf(fj[j], hi.y, v[5]);
        v[6] = fmaf(fj[j], hi.z, v[6]);
        v[7] = fmaf(fj[j], hi.w, v[7]);
    }
    #pragma unroll
    for (int k = 0; k < 8; ++k) as[e0 + k] = v[k] * invZ;
    __syncthreads();

    int o  = t & 255;
    int cp = t >> 8;
    int hd = half * 256 + o;
    int ho = hd >> 6;
    float a0 = 0.f, a1 = 0.f, a2 = 0.f, a3 = 0.f;
    const float* wp  = Wkv + DCH + hd;
    const float* apr = as + ho * DCH;
    int cbeg = cp * 256;
    #pragma unroll 4
    for (int c = cbeg; c < cbeg + 256; c += 4) {
        a0 = fmaf(apr[c],     wp[(size_t)c * (2 * DCH)],       a0);
        a1 = fmaf(apr[c + 1], wp[(size_t)(c + 1) * (2 * DCH)], a1);
        a2 = fmaf(apr[c + 2], wp[(size_t)(c + 2) * (2 * DCH)], a2);
        a3 = fmaf(apr[c + 3], wp[(size_t)(c + 3) * (2 * DCH)], a3);
    }
    red[cp][o] = (a0 + a1) + (a2 + a3);
    __syncthreads();
    if (t < 256) {
        int hd2 = half * 256 + t;
        out[(size_t)b * DCH + hd2] = bkv[DCH + hd2] + red[0][t] + red[1][t];
    }
}

// ---------------------------------------------------------------------------
extern "C" void kernel_launch(void* const* d_in, const int* in_sizes, int n_in,
                              void* d_out, int out_size, void* d_ws, size_t ws_size,
                              hipStream_t stream) {
    const float* x   = (const float*)d_in[0];   // (64, 512, 32, 32)
    const float* q   = (const float*)d_in[1];   // (1, 8, 1, 64)
    const float* Wkv = (const float*)d_in[2];   // (512, 1024)
    const float* bkv = (const float*)d_in[3];   // (1024,)
    float* out = (float*)d_out;                 // (64, 512)

    float* ws    = (float*)d_ws;
    float* wqT   = ws;                                         // 512*8
    float* bias  = wqT + DCH * NH;                             // 8*1024
    float* apart = bias + NH * NPOS;                           // 16*64*4096 = 16.8 MB
    float* mz    = apart + (size_t)NSPLIT * BATCH * NH * DCH;  // 16*64*16

    hipLaunchKernelGGL(k_prep,  dim3(6),             dim3(256), 0, stream, q, Wkv, bkv, wqT, bias);
    hipLaunchKernelGGL(k_flash, dim3(NSPLIT, BATCH), dim3(512), 0, stream, x, wqT, bias, apart, mz);
    hipLaunchKernelGGL(k_comb,  dim3(BATCH, 2),      dim3(512), 0, stream, apart, mz, Wkv, bkv, out);
}